// Round 11
// baseline (3296.835 us; speedup 1.0000x reference)
//
#include <hip/hip_runtime.h>
#include <hip/hip_bf16.h>

#define BSZ 32
#define TT 50
#define NN 192
#define HH 32
#define NSTEP (TT - 1)
#define NODES_PER_BLK 8
#define BLKS_PER_B (NN / NODES_PER_BLK)   // 24
#define NBLK (BSZ * BLKS_PER_B)           // 768

typedef __attribute__((ext_vector_type(8))) short bf16x8;
typedef __attribute__((ext_vector_type(8))) _Float16 f16x8;
typedef __attribute__((ext_vector_type(2))) _Float16 f16x2;
typedef __attribute__((ext_vector_type(4))) float f32x4;

#define MFMA16(A, B, C) __builtin_amdgcn_mfma_f32_16x16x32_bf16((A), (B), (C), 0, 0, 0)
#define MFMAH(A, B, C)  __builtin_amdgcn_mfma_f32_16x16x32_f16((A), (B), (C), 0, 0, 0)

__device__ __forceinline__ float relu(float x) { return x > 0.0f ? x : 0.0f; }

// degree-9 odd polynomial tanh on [-1.2, 1.2], abs err <~4e-5 in-range (f32).
__device__ __forceinline__ float tanh9(float x) {
    x = fminf(1.2f, fmaxf(-1.2f, x));
    float u = x * x;
    float h = __builtin_fmaf(u, 0.0090878f, -0.0447732f);
    h = __builtin_fmaf(u, h, 0.1302534f);
    h = __builtin_fmaf(u, h, -0.3329694f);
    h = __builtin_fmaf(u, h, 1.0000104f);
    return x * h;
}
__device__ __forceinline__ float sigmoid9(float x) {
    return __builtin_fmaf(0.5f, tanh9(0.5f * x), 0.5f);
}

__device__ __forceinline__ f16x2 splat2(float v) {
    f16x2 r; r[0] = (_Float16)v; r[1] = (_Float16)v; return r;
}
__device__ __forceinline__ f16x2 tanh9h2(f16x2 x) {
    x = __builtin_elementwise_min(__builtin_elementwise_max(x, splat2(-1.2f)), splat2(1.2f));
    f16x2 u = x * x;
    f16x2 h = __builtin_elementwise_fma(u, splat2(0.0090878f), splat2(-0.0447732f));
    h = __builtin_elementwise_fma(u, h, splat2(0.1302534f));
    h = __builtin_elementwise_fma(u, h, splat2(-0.3329694f));
    h = __builtin_elementwise_fma(u, h, splat2(1.0000104f));
    return x * h;
}

union U8 { bf16x8 v; __hip_bfloat162 p[4]; };
union UH { f16x8 v; f16x2 p[4]; };

__device__ __forceinline__ void ld8(const float* p, float* x) {
    const float4* q = (const float4*)p;
    float4 a = q[0], c = q[1];
    x[0] = a.x; x[1] = a.y; x[2] = a.z; x[3] = a.w;
    x[4] = c.x; x[5] = c.y; x[6] = c.z; x[7] = c.w;
}
__device__ __forceinline__ f16x8 packh8(const float* x) {
    UH u;
#pragma unroll
    for (int i = 0; i < 8; ++i) u.v[i] = (_Float16)x[i];
    return u.v;
}
__device__ __forceinline__ void split8(const float* x, bf16x8& hi, bf16x8& lo) {
    U8 H, L;
#pragma unroll
    for (int i = 0; i < 4; ++i) {
        __hip_bfloat162 h = __float22bfloat162_rn(make_float2(x[2 * i], x[2 * i + 1]));
        float2 hf = __bfloat1622float2(h);
        H.p[i] = h;
        L.p[i] = __float22bfloat162_rn(make_float2(x[2 * i] - hf.x, x[2 * i + 1] - hf.y));
    }
    hi = H.v; lo = L.v;
}
__device__ __forceinline__ void loadB_hl(const float* Wrow, bf16x8& h, bf16x8& l) {
    float x[8];
    ld8(Wrow, x);
    split8(x, h, l);
}

// Persistent kernel v4. Exchange uses the SAME cache protocol a kernel boundary
// uses: normal cached stores -> ONE release RMW (single buffer_wbl2) -> relaxed
// spin (NO cache ops per poll) -> ONE acquire load (single buffer_inv) -> normal
// cached coalesced loads. All reused state (weights, adj, hidden, recv) lives in
// registers/LDS, so the per-step L2 invalidate is nearly free.
__global__ __launch_bounds__(512, 6) void k_all(
    const int* __restrict__ skill, const float* __restrict__ adj,
    const float* __restrict__ emb,
    const float* __restrict__ Wmsg1, const float* __restrict__ bmsg1,
    const float* __restrict__ Wmsg2, const float* __restrict__ bmsg2,
    const float* __restrict__ W_hr, const float* __restrict__ W_hi, const float* __restrict__ W_hh,
    const float* __restrict__ W_ir, const float* __restrict__ b_ir,
    const float* __restrict__ W_ii, const float* __restrict__ b_ii,
    const float* __restrict__ W_in, const float* __restrict__ b_in,
    _Float16* __restrict__ sbuf0, _Float16* __restrict__ sbuf1,
    unsigned* __restrict__ cnt, float* __restrict__ hist)
{
    __shared__ alignas(16) _Float16 spsh[NN][40];   // send_p[b] staged f16
    __shared__ alignas(16) float adjsh[8][NN];      // adj rows (loaded once)
    __shared__ alignas(16) float aggsh[16][36];     // rows 0-7 live, 8-15 zero
    __shared__ alignas(16) float hnsh[16][36];      // persistent hidden
    __shared__ alignas(16) float rvsh[8][36];       // block-local recv proj
    __shared__ float grsh[8][33], gish[8][33], gnsh[8][33], ggsh[8][33];

    const int tid = threadIdx.x;
    const int w = tid >> 6, lane = tid & 63;
    const int n16 = lane & 15, kg = lane >> 4, k8 = kg * 8;
    // Same-b blocks share blockIdx%8 (XCD grouping; perf only — correctness is
    // mapping-independent thanks to the release/acquire protocol).
    const int m = blockIdx.x;
    const int b = (m & 7) * 4 + (m >> 3) / BLKS_PER_B;
    const int grp = (m >> 3) % BLKS_PER_B;
    const int node0 = b * NN + grp * NODES_PER_BLK;  // global node base
    const int node = node0 + w;
    const int prod = w >> 1, hf = w & 1;
    const int rowb = hf * 16 + n16;

    // ---- one-time init ----
    for (int i = tid; i < 16 * 36; i += 512) { ((float*)aggsh)[i] = 0.f; ((float*)hnsh)[i] = 0.f; }
    for (int i = tid; i < 8 * 36; i += 512) ((float*)rvsh)[i] = 0.f;
    {
        const float* ar = adj + (size_t)node * NN;
        adjsh[w][lane]       = ar[lane];
        adjsh[w][lane + 64]  = ar[lane + 64];
        adjsh[w][lane + 128] = ar[lane + 128];
    }
    float b1r[8];
    ld8(bmsg1 + k8, b1r);
    f16x8 Bh0, Bh1;
    {
        float x[8];
        ld8(Wmsg2 + (size_t)n16 * HH + k8, x);        Bh0 = packh8(x);
        ld8(Wmsg2 + (size_t)(16 + n16) * HH + k8, x); Bh1 = packh8(x);
    }
    const float bb2_0 = bmsg2[n16], bb2_1 = bmsg2[16 + n16];

    bf16x8 F0h{}, F0l{}, F1h{}, F1l{}, G0h{}, G0l{};
    float bias1 = 0.f;
    if (prod == 0) {            // R gate; later S (send)
        loadB_hl(W_hr + (size_t)rowb * HH + k8, F0h, F0l);
        loadB_hl(W_ir + (size_t)rowb * HH + k8, F1h, F1l);
        bias1 = b_ir[rowb];
        loadB_hl(Wmsg1 + (size_t)rowb * 2 * HH + k8, G0h, G0l);      // W_send
    } else if (prod == 1) {     // I gate; later V (recv)
        loadB_hl(W_hi + (size_t)rowb * HH + k8, F0h, F0l);
        loadB_hl(W_ii + (size_t)rowb * HH + k8, F1h, F1l);
        bias1 = b_ii[rowb];
        loadB_hl(Wmsg1 + (size_t)rowb * 2 * HH + HH + k8, G0h, G0l); // W_recv
    } else if (prod == 2) {     // N gate
        loadB_hl(W_in + (size_t)rowb * HH + k8, F0h, F0l);
        bias1 = b_in[rowb];
    } else {                    // G = agg @ W_hh^T
        loadB_hl(W_hh + (size_t)rowb * HH + k8, F0h, F0l);
    }
    __syncthreads();

    for (int t = 0; t < NSTEP; ++t) {
        const _Float16* sbr = (t & 1) ? sbuf1 : sbuf0;
        _Float16* sbw = (t & 1) ? sbuf0 : sbuf1;

        // ---- stage send_p[b]: 768 x 16B chunks via NORMAL cached loads ----
        {
            const f16x8* src = (const f16x8*)(sbr + (size_t)b * NN * HH);  // 12288 B
            f16x8 v0 = src[tid];
            *(f16x8*)&spsh[tid >> 2][(tid & 3) * 8] = v0;
            if (tid < 256) {
                const int c = tid + 512;
                f16x8 v1 = src[c];
                *(f16x8*)&spsh[c >> 2][(c & 3) * 8] = v1;
            }
        }
        // rvp = f16(recv_local + b1)
        UH rv;
        {
            float x[8];
            ld8(&rvsh[w][k8], x);
#pragma unroll
            for (int i = 0; i < 8; ++i) rv.v[i] = (_Float16)(x[i] + b1r[i]);
        }
        __syncthreads();

        // ================= Phase A =================
        float acc0 = 0.f, acc1 = 0.f;
#pragma unroll 2
        for (int s0 = 0; s0 < NN; s0 += 16) {
            UH a, tv;
            a.v = *(const f16x8*)&spsh[s0 + n16][k8];
#pragma unroll
            for (int i = 0; i < 4; ++i)
                tv.p[i] = tanh9h2(a.p[i] + rv.p[i]);
            f32x4 c0 = MFMAH(tv.v, Bh0, ((f32x4){bb2_0, bb2_0, bb2_0, bb2_0}));
            f32x4 c1 = MFMAH(tv.v, Bh1, ((f32x4){bb2_1, bb2_1, bb2_1, bb2_1}));
            const float4 a2 = *(const float4*)&adjsh[w][s0 + 4 * kg];
            acc0 += a2.x * tanh9(c0[0]) + a2.y * tanh9(c0[1]) +
                    a2.z * tanh9(c0[2]) + a2.w * tanh9(c0[3]);
            acc1 += a2.x * tanh9(c1[0]) + a2.y * tanh9(c1[1]) +
                    a2.z * tanh9(c1[2]) + a2.w * tanh9(c1[3]);
        }
        acc0 += __shfl_xor(acc0, 16, 64); acc0 += __shfl_xor(acc0, 32, 64);
        acc1 += __shfl_xor(acc1, 16, 64); acc1 += __shfl_xor(acc1, 32, 64);
        if (kg == 0) {
            aggsh[w][n16]      = acc0 * (1.0f / (float)NN);
            aggsh[w][16 + n16] = acc1 * (1.0f / (float)NN);
        }
        __syncthreads();

        // ================= gates (8 waves: R0 R1 I0 I1 N0 N1 G0 G1) =============
        {
            bf16x8 Agh{}, Agl{}, Aih{}, Ail{};
            if (prod != 2) { float x[8]; ld8(&aggsh[n16][k8], x); split8(x, Agh, Agl); }
            if (prod <= 2) {
                float x[8];
                const float* er = emb + (size_t)skill[b * TT + t] * HH;
                ld8(er + k8, x); split8(x, Aih, Ail);
            }
            f32x4 C = {bias1, bias1, bias1, bias1};
            if (prod <= 1) {
                C = MFMA16(Agh, F0h, C); C = MFMA16(Agh, F0l, C); C = MFMA16(Agl, F0h, C);
                C = MFMA16(Aih, F1h, C); C = MFMA16(Aih, F1l, C); C = MFMA16(Ail, F1h, C);
            } else if (prod == 2) {
                C = MFMA16(Aih, F0h, C); C = MFMA16(Aih, F0l, C); C = MFMA16(Ail, F0h, C);
            } else {
                C = MFMA16(Agh, F0h, C); C = MFMA16(Agh, F0l, C); C = MFMA16(Agl, F0h, C);
            }
            float* dst = (prod == 0) ? &grsh[0][0] : (prod == 1) ? &gish[0][0]
                       : (prod == 2) ? &gnsh[0][0] : &ggsh[0][0];
            if (kg < 2) {
#pragma unroll
                for (int j = 0; j < 4; ++j) dst[(4 * kg + j) * 33 + rowb] = C[j];
            }
        }
        __syncthreads();

        // ================= elementwise: hn (LDS-resident hidden) ================
        if (tid < 256) {
            const int row = tid >> 5, h = tid & 31;
            const float rg = sigmoid9(grsh[row][h]);
            const float ig = sigmoid9(gish[row][h]);
            const float ns = tanh9(gnsh[row][h] + rg * ggsh[row][h]);
            const float hn = (1.f - ig) * ns + ig * hnsh[row][h];
            hnsh[row][h] = hn;
            hist[(size_t)t * (BSZ * NN * HH) + (size_t)(node0 + row) * HH + h] = hn;
        }
        __syncthreads();

        // ================= S/V projections (waves 0-3); skip at last step =======
        if (w < 4 && t < NSTEP - 1) {
            bf16x8 Hh, Hl; float x[8];
            ld8(&hnsh[n16][k8], x); split8(x, Hh, Hl);
            f32x4 C = {0.f, 0.f, 0.f, 0.f};
            C = MFMA16(Hh, G0h, C); C = MFMA16(Hh, G0l, C); C = MFMA16(Hl, G0h, C);
            if (kg < 2) {
                if ((w >> 1) == 0) {
                    // send: plain cached f16 stores (flushed by the release below)
#pragma unroll
                    for (int j = 0; j < 4; ++j)
                        sbw[(size_t)(node0 + 4 * kg + j) * HH + rowb] = (_Float16)C[j];
                } else {
#pragma unroll
                    for (int j = 0; j < 4; ++j) rvsh[4 * kg + j][rowb] = C[j];
                }
            }
        }

        // ================= per-b barrier: release once / relaxed spin / acquire once
        if (t < NSTEP - 1) {
            __syncthreads();   // compiler drains vmcnt before s_barrier -> stores in L2
            if (tid == 0) {
                // ONE release RMW: flushes this XCD's L2 (incl. our send stores) to MALL
                __hip_atomic_fetch_add(&cnt[b], 1u, __ATOMIC_RELEASE, __HIP_MEMORY_SCOPE_AGENT);
                const unsigned tgt = (unsigned)(BLKS_PER_B * (t + 1));
                while (__hip_atomic_load(&cnt[b], __ATOMIC_RELAXED, __HIP_MEMORY_SCOPE_AGENT) < tgt)
                    __builtin_amdgcn_s_sleep(1);
                // ONE acquire: invalidates L1+L2 so next staging loads see fresh data
                (void)__hip_atomic_load(&cnt[b], __ATOMIC_ACQUIRE, __HIP_MEMORY_SCOPE_AGENT);
            }
            __syncthreads();
        }
    }
}

// ---------------- final head kernel: P1/P2/O for all node-steps ----------------
#define CHUNK 8
__global__ __launch_bounds__(512, 6) void k_head(
    const float* __restrict__ hist,    // [NSTEP][BSZ*NN][HH] (post-update hidden)
    const float* __restrict__ W_o1, const float* __restrict__ b_o1,
    const float* __restrict__ W_o2, const float* __restrict__ b_o2,
    const float* __restrict__ W_o3, const float* __restrict__ b_o3,
    float* __restrict__ out)
{
    __shared__ alignas(16) float tsh[8][16][36];
    const int tid = threadIdx.x;
    const int w = tid >> 6, lane = tid & 63;
    const int n16 = lane & 15, kg = lane >> 4, k8 = kg * 8;

    bf16x8 W1h[2], W1l[2], W2h[2], W2l[2], W3h[2], W3l[2];
    float bb1[2], bb2[2], bb3[2];
#pragma unroll
    for (int hf = 0; hf < 2; ++hf) {
        const int rowb = hf * 16 + n16;
        loadB_hl(W_o1 + (size_t)rowb * HH + k8, W1h[hf], W1l[hf]); bb1[hf] = b_o1[rowb];
        loadB_hl(W_o2 + (size_t)rowb * HH + k8, W2h[hf], W2l[hf]); bb2[hf] = b_o2[rowb];
        loadB_hl(W_o3 + (size_t)rowb * HH + k8, W3h[hf], W3l[hf]); bb3[hf] = b_o3[rowb];
    }

    const int wgid = blockIdx.x * 8 + w;
#pragma unroll 1
    for (int c = 0; c < CHUNK; ++c) {
        const int cid = wgid * CHUNK + c;
        const int rc = cid % 12;
        const int tt = (cid / 12) % NSTEP;
        const int bb = cid / (12 * NSTEP);

        const float* hrow = hist + ((size_t)tt * BSZ * NN + (size_t)bb * NN + rc * 16) * HH;
        float x[8];
        bf16x8 Ah, Al;
        ld8(hrow + (size_t)n16 * HH + k8, x);
        split8(x, Ah, Al);

#pragma unroll
        for (int hf = 0; hf < 2; ++hf) {
            f32x4 C = {bb1[hf], bb1[hf], bb1[hf], bb1[hf]};
            C = MFMA16(Ah, W1h[hf], C); C = MFMA16(Ah, W1l[hf], C); C = MFMA16(Al, W1h[hf], C);
#pragma unroll
            for (int j = 0; j < 4; ++j) tsh[w][4 * kg + j][hf * 16 + n16] = relu(C[j]);
        }
        ld8(&tsh[w][n16][k8], x);
        split8(x, Ah, Al);

#pragma unroll
        for (int hf = 0; hf < 2; ++hf) {
            f32x4 C = {bb2[hf], bb2[hf], bb2[hf], bb2[hf]};
            C = MFMA16(Ah, W2h[hf], C); C = MFMA16(Ah, W2l[hf], C); C = MFMA16(Al, W2h[hf], C);
#pragma unroll
            for (int j = 0; j < 4; ++j) tsh[w][4 * kg + j][hf * 16 + n16] = relu(C[j]);
        }
        ld8(&tsh[w][n16][k8], x);
        split8(x, Ah, Al);

        float* obase = out + (((size_t)bb * NSTEP + tt) * NN + rc * 16) * HH;
#pragma unroll
        for (int hf = 0; hf < 2; ++hf) {
            f32x4 C = {bb3[hf], bb3[hf], bb3[hf], bb3[hf]};
            C = MFMA16(Ah, W3h[hf], C); C = MFMA16(Ah, W3l[hf], C); C = MFMA16(Al, W3h[hf], C);
#pragma unroll
            for (int j = 0; j < 4; ++j)
                obase[(size_t)(4 * kg + j) * HH + hf * 16 + n16] = C[j];
        }
    }
}

extern "C" void kernel_launch(void* const* d_in, const int* in_sizes, int n_in,
                              void* d_out, int out_size, void* d_ws, size_t ws_size,
                              hipStream_t stream) {
    const int*   skill = (const int*)d_in[0];
    const float* adj   = (const float*)d_in[1];
    const float* emb   = (const float*)d_in[2];
    const float* Wmsg1 = (const float*)d_in[3];
    const float* bmsg1 = (const float*)d_in[4];
    const float* Wmsg2 = (const float*)d_in[5];
    const float* bmsg2 = (const float*)d_in[6];
    const float* W_hr  = (const float*)d_in[7];
    const float* W_hi  = (const float*)d_in[8];
    const float* W_hh  = (const float*)d_in[9];
    const float* W_ir  = (const float*)d_in[10];
    const float* b_ir  = (const float*)d_in[11];
    const float* W_ii  = (const float*)d_in[12];
    const float* b_ii  = (const float*)d_in[13];
    const float* W_in  = (const float*)d_in[14];
    const float* b_in  = (const float*)d_in[15];
    const float* W_o1  = (const float*)d_in[16];
    const float* b_o1  = (const float*)d_in[17];
    const float* W_o2  = (const float*)d_in[18];
    const float* b_o2  = (const float*)d_in[19];
    const float* W_o3  = (const float*)d_in[20];
    const float* b_o3  = (const float*)d_in[21];
    float* out = (float*)d_out;

    const size_t NH = (size_t)BSZ * NN * HH;     // 196608 elements
    char* base = (char*)d_ws;
    _Float16* sb0h = (_Float16*)base;                             // 384 KB (zeroed)
    unsigned* cnt  = (unsigned*)(base + NH * 2);                  // 128 B  (zeroed)
    float*    hist = (float*)(base + NH * 2 + 128);               // 49 slabs of hn
    _Float16* sb1h = (_Float16*)((char*)hist + (size_t)NSTEP * NH * 4);

    (void)hipMemsetAsync(d_ws, 0, NH * 2 + 128, stream);

    k_all<<<NBLK, 512, 0, stream>>>(
        skill, adj, emb, Wmsg1, bmsg1, Wmsg2, bmsg2,
        W_hr, W_hi, W_hh, W_ir, b_ir, W_ii, b_ii, W_in, b_in,
        sb0h, sb1h, cnt, hist);

    // head over all 49*6144 node-steps
    k_head<<<294, 512, 0, stream>>>(hist, W_o1, b_o1, W_o2, b_o2, W_o3, b_o3, out);
}

// Round 12
// 1212.371 us; speedup vs baseline: 2.7193x; 2.7193x over previous
//
#include <hip/hip_runtime.h>
#include <hip/hip_bf16.h>

#define BSZ 32
#define TT 50
#define NN 192
#define HH 32
#define NSTEP (TT - 1)
#define NODES_PER_BLK 8
#define NBLK (BSZ * NN / NODES_PER_BLK)   // 768

typedef __attribute__((ext_vector_type(8))) short bf16x8;
typedef __attribute__((ext_vector_type(8))) _Float16 f16x8;
typedef __attribute__((ext_vector_type(2))) _Float16 f16x2;
typedef __attribute__((ext_vector_type(4))) float f32x4;

#define MFMA16(A, B, C) __builtin_amdgcn_mfma_f32_16x16x32_bf16((A), (B), (C), 0, 0, 0)
#define MFMAH(A, B, C)  __builtin_amdgcn_mfma_f32_16x16x32_f16((A), (B), (C), 0, 0, 0)

// 2*log2(e): tanh(x) = 1 - 2/(1 + 2^(C2*x))
#define C2 2.885390081777927f

#if defined(__has_builtin)
#if __has_builtin(__builtin_amdgcn_exp2f)
#define EXP2(x) __builtin_amdgcn_exp2f(x)
#endif
#endif
#ifndef EXP2
#define EXP2(x) __expf(0.69314718056f * (x))
#endif

__device__ __forceinline__ float fast_rcp(float x) { return __builtin_amdgcn_rcpf(x); }
__device__ __forceinline__ float relu(float x) { return x > 0.0f ? x : 0.0f; }

// degree-9 odd polynomial tanh on [-1.2, 1.2] (f32) — used in gates/hn only.
__device__ __forceinline__ float tanh9(float x) {
    x = fminf(1.2f, fmaxf(-1.2f, x));
    float u = x * x;
    float h = __builtin_fmaf(u, 0.0090878f, -0.0447732f);
    h = __builtin_fmaf(u, h, 0.1302534f);
    h = __builtin_fmaf(u, h, -0.3329694f);
    h = __builtin_fmaf(u, h, 1.0000104f);
    return x * h;
}
__device__ __forceinline__ float sigmoid9(float x) {
    return __builtin_fmaf(0.5f, tanh9(0.5f * x), 0.5f);
}

__device__ __forceinline__ f16x2 splat2(float v) {
    f16x2 r; r[0] = (_Float16)v; r[1] = (_Float16)v; return r;
}
// packed-f16 tanh poly (VALU pipe)
__device__ __forceinline__ f16x2 tanh9h2(f16x2 x) {
    x = __builtin_elementwise_min(__builtin_elementwise_max(x, splat2(-1.2f)), splat2(1.2f));
    f16x2 u = x * x;
    f16x2 h = __builtin_elementwise_fma(u, splat2(0.0090878f), splat2(-0.0447732f));
    h = __builtin_elementwise_fma(u, h, splat2(0.1302534f));
    h = __builtin_elementwise_fma(u, h, splat2(-0.3329694f));
    h = __builtin_elementwise_fma(u, h, splat2(1.0000104f));
    return x * h;
}

union U8 { bf16x8 v; __hip_bfloat162 p[4]; };
union UH { f16x8 v; f16x2 p[4]; };

__device__ __forceinline__ void ld8(const float* p, float* x) {
    const float4* q = (const float4*)p;
    float4 a = q[0], c = q[1];
    x[0] = a.x; x[1] = a.y; x[2] = a.z; x[3] = a.w;
    x[4] = c.x; x[5] = c.y; x[6] = c.z; x[7] = c.w;
}
__device__ __forceinline__ f16x8 packh8(const float* x) {
    UH u;
#pragma unroll
    for (int i = 0; i < 8; ++i) u.v[i] = (_Float16)x[i];
    return u.v;
}
__device__ __forceinline__ void split8(const float* x, bf16x8& hi, bf16x8& lo) {
    U8 H, L;
#pragma unroll
    for (int i = 0; i < 4; ++i) {
        __hip_bfloat162 h = __float22bfloat162_rn(make_float2(x[2 * i], x[2 * i + 1]));
        float2 hf = __bfloat1622float2(h);
        H.p[i] = h;
        L.p[i] = __float22bfloat162_rn(make_float2(x[2 * i] - hf.x, x[2 * i + 1] - hf.y));
    }
    hi = H.v; lo = L.v;
}
__device__ __forceinline__ void loadB_hl(const float* Wrow, bf16x8& h, bf16x8& l) {
    float x[8];
    ld8(Wrow, x);
    split8(x, h, l);
}

// ---------------- per-step kernel: agg + gates + hn + send/recv ----------------
// 512 thr = 8 waves = 8 nodes. msg1-tanh: packed-f16 poly (VALU pipe);
// msg2-tanh: exp2+rcp (trans pipe), C2 folded into B-frags, adj folded via A0.
__global__ __launch_bounds__(512, 6) void k_step(
    const int* __restrict__ skill, const float* __restrict__ adj,
    const float* __restrict__ emb,
    const float* __restrict__ Wmsg1, const float* __restrict__ bmsg1,
    const float* __restrict__ Wmsg2, const float* __restrict__ bmsg2,
    const float* __restrict__ W_hr, const float* __restrict__ W_hi, const float* __restrict__ W_hh,
    const float* __restrict__ W_ir, const float* __restrict__ b_ir,
    const float* __restrict__ W_ii, const float* __restrict__ b_ii,
    const float* __restrict__ W_in, const float* __restrict__ b_in,
    const _Float16* __restrict__ sbr, _Float16* __restrict__ sbw,
    float* __restrict__ rbuf,
    const float* __restrict__ hprev, float* __restrict__ hcur, int t)
{
    __shared__ alignas(16) _Float16 spsh[NN][40];   // send_p[b] staged f16
    __shared__ alignas(16) float adjsh[8][NN];
    __shared__ alignas(16) float aggsh[16][36];
    __shared__ alignas(16) float hnsh[16][36];
    __shared__ float grsh[8][33], gish[8][33], gnsh[8][33], ggsh[8][33];

    const int tid = threadIdx.x;
    const int w = tid >> 6, lane = tid & 63;
    const int n16 = lane & 15, kg = lane >> 4, k8 = kg * 8;
    const int node0 = blockIdx.x * NODES_PER_BLK;
    const int b = node0 / NN;
    const int node = node0 + w;
    const int prod = w >> 1, hf = w & 1;
    const int rowb = hf * 16 + n16;

    // prefetch hprev early (used after 3 barriers)
    float hold = 0.f;
    if (tid < 256)
        hold = hprev[(size_t)(node0 + (tid >> 5)) * HH + (tid & 31)];

    // zero batch rows 8-15 (fresh LDS every launch)
    for (int i = tid; i < 8 * 36; i += 512) {
        ((float*)aggsh)[8 * 36 + i] = 0.f;
        ((float*)hnsh)[8 * 36 + i] = 0.f;
    }

    // stage send_p[b] (12 KB f16, L2-warm) — 768 chunks of 16B
    {
        const f16x8* src = (const f16x8*)(sbr + (size_t)b * NN * HH);
        f16x8 v0 = src[tid];
        *(f16x8*)&spsh[tid >> 2][(tid & 3) * 8] = v0;
        if (tid < 256) {
            const int c = tid + 512;
            f16x8 v1 = src[c];
            *(f16x8*)&spsh[c >> 2][(c & 3) * 8] = v1;
        }
    }
    // adj row + A0 = sum(adj)
    float A0w;
    {
        const float* ar = adj + (size_t)node * NN;
        float a0 = ar[lane], a1 = ar[lane + 64], a2v = ar[lane + 128];
        adjsh[w][lane] = a0; adjsh[w][lane + 64] = a1; adjsh[w][lane + 128] = a2v;
        float s = a0 + a1 + a2v;
#pragma unroll
        for (int mm = 1; mm < 64; mm <<= 1) s += __shfl_xor(s, mm, 64);
        A0w = s;
    }
    // rvp = f16(recv + b1)
    UH rv;
    {
        float xr[8], xc[8];
        ld8(rbuf + (size_t)node * HH + k8, xr);
        ld8(bmsg1 + k8, xc);
#pragma unroll
        for (int i = 0; i < 8; ++i) rv.v[i] = (_Float16)(xr[i] + xc[i]);
    }
    // phase-A B-frags: C2 * W2^T in f16 (C2 folded so MFMA outputs the exp2 arg)
    f16x8 Bh0, Bh1;
    {
        float x[8];
        ld8(Wmsg2 + (size_t)n16 * HH + k8, x);
#pragma unroll
        for (int i = 0; i < 8; ++i) x[i] *= C2;
        Bh0 = packh8(x);
        ld8(Wmsg2 + (size_t)(16 + n16) * HH + k8, x);
#pragma unroll
        for (int i = 0; i < 8; ++i) x[i] *= C2;
        Bh1 = packh8(x);
    }
    const float cb2_0 = C2 * bmsg2[n16], cb2_1 = C2 * bmsg2[16 + n16];

    // per-wave gate weight fragments (role = prod, half = hf) — bf16 hi/lo
    bf16x8 F0h{}, F0l{}, F1h{}, F1l{}, G0h{}, G0l{};
    float bias1 = 0.f;
    if (prod == 0) {            // R gate; later S (send)
        loadB_hl(W_hr + (size_t)rowb * HH + k8, F0h, F0l);
        loadB_hl(W_ir + (size_t)rowb * HH + k8, F1h, F1l);
        bias1 = b_ir[rowb];
        loadB_hl(Wmsg1 + (size_t)rowb * 2 * HH + k8, G0h, G0l);      // W_send
    } else if (prod == 1) {     // I gate; later V (recv)
        loadB_hl(W_hi + (size_t)rowb * HH + k8, F0h, F0l);
        loadB_hl(W_ii + (size_t)rowb * HH + k8, F1h, F1l);
        bias1 = b_ii[rowb];
        loadB_hl(Wmsg1 + (size_t)rowb * 2 * HH + HH + k8, G0h, G0l); // W_recv
    } else if (prod == 2) {     // N gate
        loadB_hl(W_in + (size_t)rowb * HH + k8, F0h, F0l);
        bias1 = b_in[rowb];
    } else {                    // G = agg @ W_hh^T
        loadB_hl(W_hh + (size_t)rowb * HH + k8, F0h, F0l);
    }
    __syncthreads();

    // ================= Phase A (poly on VALU pipe, exp2/rcp on trans pipe) ======
    float acc0 = 0.f, acc1 = 0.f;   // accumulate sum(adj * inv)
#pragma unroll 2
    for (int s0 = 0; s0 < NN; s0 += 16) {
        UH a, tv;
        a.v = *(const f16x8*)&spsh[s0 + n16][k8];
#pragma unroll
        for (int i = 0; i < 4; ++i)
            tv.p[i] = tanh9h2(a.p[i] + rv.p[i]);
        f32x4 c0 = MFMAH(tv.v, Bh0, ((f32x4){cb2_0, cb2_0, cb2_0, cb2_0}));
        f32x4 c1 = MFMAH(tv.v, Bh1, ((f32x4){cb2_1, cb2_1, cb2_1, cb2_1}));
        const float4 a2 = *(const float4*)&adjsh[w][s0 + 4 * kg];
        // tanh = 1 - 2*inv, inv = 1/(1+2^(C2*y)); sum(adj*tanh) = A0 - 2*sum(adj*inv)
        acc0 = __builtin_fmaf(a2.x, fast_rcp(1.f + EXP2(c0[0])), acc0);
        acc0 = __builtin_fmaf(a2.y, fast_rcp(1.f + EXP2(c0[1])), acc0);
        acc0 = __builtin_fmaf(a2.z, fast_rcp(1.f + EXP2(c0[2])), acc0);
        acc0 = __builtin_fmaf(a2.w, fast_rcp(1.f + EXP2(c0[3])), acc0);
        acc1 = __builtin_fmaf(a2.x, fast_rcp(1.f + EXP2(c1[0])), acc1);
        acc1 = __builtin_fmaf(a2.y, fast_rcp(1.f + EXP2(c1[1])), acc1);
        acc1 = __builtin_fmaf(a2.z, fast_rcp(1.f + EXP2(c1[2])), acc1);
        acc1 = __builtin_fmaf(a2.w, fast_rcp(1.f + EXP2(c1[3])), acc1);
    }
    acc0 += __shfl_xor(acc0, 16, 64); acc0 += __shfl_xor(acc0, 32, 64);
    acc1 += __shfl_xor(acc1, 16, 64); acc1 += __shfl_xor(acc1, 32, 64);
    if (kg == 0) {
        aggsh[w][n16]      = (A0w - 2.f * acc0) * (1.0f / (float)NN);
        aggsh[w][16 + n16] = (A0w - 2.f * acc1) * (1.0f / (float)NN);
    }
    __syncthreads();

    // ================= gates (8 waves: R0 R1 I0 I1 N0 N1 G0 G1) =================
    {
        bf16x8 Agh{}, Agl{}, Aih{}, Ail{};
        if (prod != 2) { float x[8]; ld8(&aggsh[n16][k8], x); split8(x, Agh, Agl); }
        if (prod <= 2) {
            float x[8];
            const float* er = emb + (size_t)skill[b * TT + t] * HH;
            ld8(er + k8, x); split8(x, Aih, Ail);
        }
        f32x4 C = {bias1, bias1, bias1, bias1};
        if (prod <= 1) {
            C = MFMA16(Agh, F0h, C); C = MFMA16(Agh, F0l, C); C = MFMA16(Agl, F0h, C);
            C = MFMA16(Aih, F1h, C); C = MFMA16(Aih, F1l, C); C = MFMA16(Ail, F1h, C);
        } else if (prod == 2) {
            C = MFMA16(Aih, F0h, C); C = MFMA16(Aih, F0l, C); C = MFMA16(Ail, F0h, C);
        } else {
            C = MFMA16(Agh, F0h, C); C = MFMA16(Agh, F0l, C); C = MFMA16(Agl, F0h, C);
        }
        float* dst = (prod == 0) ? &grsh[0][0] : (prod == 1) ? &gish[0][0]
                   : (prod == 2) ? &gnsh[0][0] : &ggsh[0][0];
        if (kg < 2) {
#pragma unroll
            for (int j = 0; j < 4; ++j) dst[(4 * kg + j) * 33 + rowb] = C[j];
        }
    }
    __syncthreads();

    // ================= elementwise: hn =================
    if (tid < 256) {
        const int row = tid >> 5, h = tid & 31;
        const float rg = sigmoid9(grsh[row][h]);
        const float ig = sigmoid9(gish[row][h]);
        const float ns = tanh9(gnsh[row][h] + rg * ggsh[row][h]);
        const float hn = (1.f - ig) * ns + ig * hold;
        hnsh[row][h] = hn;
        hcur[(size_t)(node0 + row) * HH + h] = hn;
    }
    __syncthreads();

    // ================= S/V projections (waves 0-3) =================
    if (w < 4) {
        const int p2 = w >> 1;      // 0:S 1:V
        bf16x8 Hh, Hl; float x[8];
        ld8(&hnsh[n16][k8], x); split8(x, Hh, Hl);
        f32x4 C = {0.f, 0.f, 0.f, 0.f};
        C = MFMA16(Hh, G0h, C); C = MFMA16(Hh, G0l, C); C = MFMA16(Hl, G0h, C);
        if (kg < 2) {
            if (p2 == 0) {
#pragma unroll
                for (int j = 0; j < 4; ++j)
                    sbw[(size_t)(node0 + 4 * kg + j) * HH + rowb] = (_Float16)C[j];
            } else {
#pragma unroll
                for (int j = 0; j < 4; ++j)
                    rbuf[(size_t)(node0 + 4 * kg + j) * HH + rowb] = C[j];
            }
        }
    }
}

// ---------------- final head kernel: P1/P2/O for all node-steps ----------------
#define CHUNK 8
__global__ __launch_bounds__(512, 6) void k_head(
    const float* __restrict__ hist,    // [NSTEP][BSZ*NN][HH] (post-update hidden)
    const float* __restrict__ W_o1, const float* __restrict__ b_o1,
    const float* __restrict__ W_o2, const float* __restrict__ b_o2,
    const float* __restrict__ W_o3, const float* __restrict__ b_o3,
    float* __restrict__ out)
{
    __shared__ alignas(16) float tsh[8][16][36];
    const int tid = threadIdx.x;
    const int w = tid >> 6, lane = tid & 63;
    const int n16 = lane & 15, kg = lane >> 4, k8 = kg * 8;

    bf16x8 W1h[2], W1l[2], W2h[2], W2l[2], W3h[2], W3l[2];
    float bb1[2], bb2[2], bb3[2];
#pragma unroll
    for (int hf = 0; hf < 2; ++hf) {
        const int rowb = hf * 16 + n16;
        loadB_hl(W_o1 + (size_t)rowb * HH + k8, W1h[hf], W1l[hf]); bb1[hf] = b_o1[rowb];
        loadB_hl(W_o2 + (size_t)rowb * HH + k8, W2h[hf], W2l[hf]); bb2[hf] = b_o2[rowb];
        loadB_hl(W_o3 + (size_t)rowb * HH + k8, W3h[hf], W3l[hf]); bb3[hf] = b_o3[rowb];
    }

    const int wgid = blockIdx.x * 8 + w;
#pragma unroll 1
    for (int c = 0; c < CHUNK; ++c) {
        const int cid = wgid * CHUNK + c;
        const int rc = cid % 12;
        const int tt = (cid / 12) % NSTEP;
        const int bb = cid / (12 * NSTEP);

        const float* hrow = hist + ((size_t)tt * BSZ * NN + (size_t)bb * NN + rc * 16) * HH;
        float x[8];
        bf16x8 Ah, Al;
        ld8(hrow + (size_t)n16 * HH + k8, x);
        split8(x, Ah, Al);

        // layer 1
#pragma unroll
        for (int hf = 0; hf < 2; ++hf) {
            f32x4 C = {bb1[hf], bb1[hf], bb1[hf], bb1[hf]};
            C = MFMA16(Ah, W1h[hf], C); C = MFMA16(Ah, W1l[hf], C); C = MFMA16(Al, W1h[hf], C);
#pragma unroll
            for (int j = 0; j < 4; ++j) tsh[w][4 * kg + j][hf * 16 + n16] = relu(C[j]);
        }
        ld8(&tsh[w][n16][k8], x);
        split8(x, Ah, Al);

        // layer 2
#pragma unroll
        for (int hf = 0; hf < 2; ++hf) {
            f32x4 C = {bb2[hf], bb2[hf], bb2[hf], bb2[hf]};
            C = MFMA16(Ah, W2h[hf], C); C = MFMA16(Ah, W2l[hf], C); C = MFMA16(Al, W2h[hf], C);
#pragma unroll
            for (int j = 0; j < 4; ++j) tsh[w][4 * kg + j][hf * 16 + n16] = relu(C[j]);
        }
        ld8(&tsh[w][n16][k8], x);
        split8(x, Ah, Al);

        // layer 3 -> out[bb][tt][rc*16 + row][h]
        float* obase = out + (((size_t)bb * NSTEP + tt) * NN + rc * 16) * HH;
#pragma unroll
        for (int hf = 0; hf < 2; ++hf) {
            f32x4 C = {bb3[hf], bb3[hf], bb3[hf], bb3[hf]};
            C = MFMA16(Ah, W3h[hf], C); C = MFMA16(Ah, W3l[hf], C); C = MFMA16(Al, W3h[hf], C);
#pragma unroll
            for (int j = 0; j < 4; ++j)
                obase[(size_t)(4 * kg + j) * HH + hf * 16 + n16] = C[j];
        }
    }
}

extern "C" void kernel_launch(void* const* d_in, const int* in_sizes, int n_in,
                              void* d_out, int out_size, void* d_ws, size_t ws_size,
                              hipStream_t stream) {
    const int*   skill = (const int*)d_in[0];
    const float* adj   = (const float*)d_in[1];
    const float* emb   = (const float*)d_in[2];
    const float* Wmsg1 = (const float*)d_in[3];
    const float* bmsg1 = (const float*)d_in[4];
    const float* Wmsg2 = (const float*)d_in[5];
    const float* bmsg2 = (const float*)d_in[6];
    const float* W_hr  = (const float*)d_in[7];
    const float* W_hi  = (const float*)d_in[8];
    const float* W_hh  = (const float*)d_in[9];
    const float* W_ir  = (const float*)d_in[10];
    const float* b_ir  = (const float*)d_in[11];
    const float* W_ii  = (const float*)d_in[12];
    const float* b_ii  = (const float*)d_in[13];
    const float* W_in  = (const float*)d_in[14];
    const float* b_in  = (const float*)d_in[15];
    const float* W_o1  = (const float*)d_in[16];
    const float* b_o1  = (const float*)d_in[17];
    const float* W_o2  = (const float*)d_in[18];
    const float* b_o2  = (const float*)d_in[19];
    const float* W_o3  = (const float*)d_in[20];
    const float* b_o3  = (const float*)d_in[21];
    float* out = (float*)d_out;

    const size_t NH = (size_t)BSZ * NN * HH;     // 196608 elements
    char* base = (char*)d_ws;
    _Float16* sb0h = (_Float16*)base;                              // NH f16 (zeroed)
    float*    rbuf = (float*)(base + NH * 2);                      // NH f32 (zeroed)
    float*    hist = (float*)(base + NH * 2 + NH * 4);             // (1+NSTEP) slabs f32
    _Float16* sb1h = (_Float16*)(base + NH * 2 + NH * 4 + (size_t)(1 + NSTEP) * NH * 4);

    // zero: send ping (read at t=0), recv buf, hidden slab 0
    (void)hipMemsetAsync(d_ws, 0, NH * 2 + NH * 4 + NH * 4, stream);

    for (int t = 0; t < NSTEP; ++t) {
        const _Float16* sbr = (t & 1) ? sb1h : sb0h;
        _Float16*       sbw = (t & 1) ? sb0h : sb1h;
        const float* hprev = hist + (size_t)t * NH;
        float*       hcur  = hist + (size_t)(t + 1) * NH;
        k_step<<<NBLK, 512, 0, stream>>>(
            skill, adj, emb, Wmsg1, bmsg1, Wmsg2, bmsg2,
            W_hr, W_hi, W_hh, W_ir, b_ir, W_ii, b_ii, W_in, b_in,
            sbr, sbw, rbuf, hprev, hcur, t);
    }
    // head over all 49*6144 node-steps
    k_head<<<294, 512, 0, stream>>>(hist + NH, W_o1, b_o1, W_o2, b_o2, W_o3, b_o3, out);
}

// Round 13
// 999.271 us; speedup vs baseline: 3.2992x; 1.2133x over previous
//
#include <hip/hip_runtime.h>
#include <hip/hip_bf16.h>

#define BSZ 32
#define TT 50
#define NN 192
#define HH 32
#define NSTEP (TT - 1)
#define NODES_PER_BLK 8
#define BLKS_PER_B (NN / NODES_PER_BLK)   // 24
#define NBLK (BSZ * BLKS_PER_B)           // 768

#define BSLAB_F16 8192                    // f16 per b within a slab (6144 data + pad)
#define SLAB_F16 (BSZ * BSLAB_F16)        // 262144 f16 = 512 KB per step

typedef __attribute__((ext_vector_type(8))) short bf16x8;
typedef __attribute__((ext_vector_type(8))) _Float16 f16x8;
typedef __attribute__((ext_vector_type(2))) _Float16 f16x2;
typedef __attribute__((ext_vector_type(4))) float f32x4;

#define MFMA16(A, B, C) __builtin_amdgcn_mfma_f32_16x16x32_bf16((A), (B), (C), 0, 0, 0)
#define MFMAH(A, B, C)  __builtin_amdgcn_mfma_f32_16x16x32_f16((A), (B), (C), 0, 0, 0)

__device__ __forceinline__ float relu(float x) { return x > 0.0f ? x : 0.0f; }

// degree-9 odd polynomial tanh on [-1.2, 1.2], abs err <~4e-5 in-range (f32).
__device__ __forceinline__ float tanh9(float x) {
    x = fminf(1.2f, fmaxf(-1.2f, x));
    float u = x * x;
    float h = __builtin_fmaf(u, 0.0090878f, -0.0447732f);
    h = __builtin_fmaf(u, h, 0.1302534f);
    h = __builtin_fmaf(u, h, -0.3329694f);
    h = __builtin_fmaf(u, h, 1.0000104f);
    return x * h;
}
__device__ __forceinline__ float sigmoid9(float x) {
    return __builtin_fmaf(0.5f, tanh9(0.5f * x), 0.5f);
}

__device__ __forceinline__ f16x2 splat2(float v) {
    f16x2 r; r[0] = (_Float16)v; r[1] = (_Float16)v; return r;
}
__device__ __forceinline__ f16x2 tanh9h2(f16x2 x) {
    x = __builtin_elementwise_min(__builtin_elementwise_max(x, splat2(-1.2f)), splat2(1.2f));
    f16x2 u = x * x;
    f16x2 h = __builtin_elementwise_fma(u, splat2(0.0090878f), splat2(-0.0447732f));
    h = __builtin_elementwise_fma(u, h, splat2(0.1302534f));
    h = __builtin_elementwise_fma(u, h, splat2(-0.3329694f));
    h = __builtin_elementwise_fma(u, h, splat2(1.0000104f));
    return x * h;
}

union U8 { bf16x8 v; __hip_bfloat162 p[4]; };
union UH { f16x8 v; f16x2 p[4]; };

__device__ __forceinline__ void ld8(const float* p, float* x) {
    const float4* q = (const float4*)p;
    float4 a = q[0], c = q[1];
    x[0] = a.x; x[1] = a.y; x[2] = a.z; x[3] = a.w;
    x[4] = c.x; x[5] = c.y; x[6] = c.z; x[7] = c.w;
}
__device__ __forceinline__ f16x8 packh8(const float* x) {
    UH u;
#pragma unroll
    for (int i = 0; i < 8; ++i) u.v[i] = (_Float16)x[i];
    return u.v;
}
__device__ __forceinline__ void split8(const float* x, bf16x8& hi, bf16x8& lo) {
    U8 H, L;
#pragma unroll
    for (int i = 0; i < 4; ++i) {
        __hip_bfloat162 h = __float22bfloat162_rn(make_float2(x[2 * i], x[2 * i + 1]));
        float2 hf = __bfloat1622float2(h);
        H.p[i] = h;
        L.p[i] = __float22bfloat162_rn(make_float2(x[2 * i] - hf.x, x[2 * i + 1] - hf.y));
    }
    hi = H.v; lo = L.v;
}
__device__ __forceinline__ void loadB_hl(const float* Wrow, bf16x8& h, bf16x8& l) {
    float x[8];
    ld8(Wrow, x);
    split8(x, h, l);
}

// Persistent kernel v5. Exchange: per-STEP slabs (consumer addresses are always
// first-touch -> no stale L1/L2 possible, XCD-mapping-independent). Producer
// packs send_p through a 512B LDS bounce and writes 32 x 16B global_store_dwordx4
// with sc1 (write-through to MALL). Consumer uses PLAIN cached vector loads.
// Flags: relaxed agent atomics (proven r9/r11), ordered by wave-0 vmcnt(0).
__global__ __launch_bounds__(512, 6) void k_all(
    const int* __restrict__ skill, const float* __restrict__ adj,
    const float* __restrict__ emb,
    const float* __restrict__ Wmsg1, const float* __restrict__ bmsg1,
    const float* __restrict__ Wmsg2, const float* __restrict__ bmsg2,
    const float* __restrict__ W_hr, const float* __restrict__ W_hi, const float* __restrict__ W_hh,
    const float* __restrict__ W_ir, const float* __restrict__ b_ir,
    const float* __restrict__ W_ii, const float* __restrict__ b_ii,
    const float* __restrict__ W_in, const float* __restrict__ b_in,
    _Float16* __restrict__ sbuf, unsigned* __restrict__ cnt, float* __restrict__ hist)
{
    __shared__ alignas(16) _Float16 spsh[NN][40];   // send_p[b] staged f16
    __shared__ alignas(16) float adjsh[8][NN];      // adj rows (loaded once)
    __shared__ alignas(16) float aggsh[16][36];     // rows 0-7 live, 8-15 zero
    __shared__ alignas(16) float hnsh[16][36];      // persistent hidden
    __shared__ alignas(16) float rvsh[8][36];       // block-local recv proj
    __shared__ alignas(16) _Float16 ssh[8][32];     // send bounce (512 B)
    __shared__ float grsh[8][33], gish[8][33], gnsh[8][33], ggsh[8][33];

    const int tid = threadIdx.x;
    const int w = tid >> 6, lane = tid & 63;
    const int n16 = lane & 15, kg = lane >> 4, k8 = kg * 8;
    // Same-b blocks share blockIdx%8 (XCD grouping; PERF only — correctness is
    // mapping-independent via first-touch slabs + sc1 write-through).
    const int m = blockIdx.x;
    const int b = (m & 7) * 4 + (m >> 3) / BLKS_PER_B;
    const int grp = (m >> 3) % BLKS_PER_B;
    const int node0 = b * NN + grp * NODES_PER_BLK;  // global node base
    const int node = node0 + w;
    const int prod = w >> 1, hf = w & 1;
    const int rowb = hf * 16 + n16;

    // ---- one-time init ----
    for (int i = tid; i < 16 * 36; i += 512) { ((float*)aggsh)[i] = 0.f; ((float*)hnsh)[i] = 0.f; }
    for (int i = tid; i < 8 * 36; i += 512) ((float*)rvsh)[i] = 0.f;
    {
        const float* ar = adj + (size_t)node * NN;
        adjsh[w][lane]       = ar[lane];
        adjsh[w][lane + 64]  = ar[lane + 64];
        adjsh[w][lane + 128] = ar[lane + 128];
    }
    float b1r[8];
    ld8(bmsg1 + k8, b1r);
    f16x8 Bh0, Bh1;
    {
        float x[8];
        ld8(Wmsg2 + (size_t)n16 * HH + k8, x);        Bh0 = packh8(x);
        ld8(Wmsg2 + (size_t)(16 + n16) * HH + k8, x); Bh1 = packh8(x);
    }
    const float bb2_0 = bmsg2[n16], bb2_1 = bmsg2[16 + n16];

    bf16x8 F0h{}, F0l{}, F1h{}, F1l{}, G0h{}, G0l{};
    float bias1 = 0.f;
    if (prod == 0) {            // R gate; later S (send)
        loadB_hl(W_hr + (size_t)rowb * HH + k8, F0h, F0l);
        loadB_hl(W_ir + (size_t)rowb * HH + k8, F1h, F1l);
        bias1 = b_ir[rowb];
        loadB_hl(Wmsg1 + (size_t)rowb * 2 * HH + k8, G0h, G0l);      // W_send
    } else if (prod == 1) {     // I gate; later V (recv)
        loadB_hl(W_hi + (size_t)rowb * HH + k8, F0h, F0l);
        loadB_hl(W_ii + (size_t)rowb * HH + k8, F1h, F1l);
        bias1 = b_ii[rowb];
        loadB_hl(Wmsg1 + (size_t)rowb * 2 * HH + HH + k8, G0h, G0l); // W_recv
    } else if (prod == 2) {     // N gate
        loadB_hl(W_in + (size_t)rowb * HH + k8, F0h, F0l);
        bias1 = b_in[rowb];
    } else {                    // G = agg @ W_hh^T
        loadB_hl(W_hh + (size_t)rowb * HH + k8, F0h, F0l);
    }
    __syncthreads();

    for (int t = 0; t < NSTEP; ++t) {
        // ---- stage send_p[b] from slab t via PLAIN cached loads (first touch) ----
        {
            const f16x8* src = (const f16x8*)(sbuf + (size_t)t * SLAB_F16 + (size_t)b * BSLAB_F16);
            f16x8 v0 = src[tid];
            *(f16x8*)&spsh[tid >> 2][(tid & 3) * 8] = v0;
            if (tid < 256) {
                const int c = tid + 512;
                f16x8 v1 = src[c];
                *(f16x8*)&spsh[c >> 2][(c & 3) * 8] = v1;
            }
        }
        // rvp = f16(recv_local + b1)
        UH rv;
        {
            float x[8];
            ld8(&rvsh[w][k8], x);
#pragma unroll
            for (int i = 0; i < 8; ++i) rv.v[i] = (_Float16)(x[i] + b1r[i]);
        }
        __syncthreads();

        // ================= Phase A =================
        float acc0 = 0.f, acc1 = 0.f;
#pragma unroll 2
        for (int s0 = 0; s0 < NN; s0 += 16) {
            UH a, tv;
            a.v = *(const f16x8*)&spsh[s0 + n16][k8];
#pragma unroll
            for (int i = 0; i < 4; ++i)
                tv.p[i] = tanh9h2(a.p[i] + rv.p[i]);
            f32x4 c0 = MFMAH(tv.v, Bh0, ((f32x4){bb2_0, bb2_0, bb2_0, bb2_0}));
            f32x4 c1 = MFMAH(tv.v, Bh1, ((f32x4){bb2_1, bb2_1, bb2_1, bb2_1}));
            const float4 a2 = *(const float4*)&adjsh[w][s0 + 4 * kg];
            acc0 += a2.x * tanh9(c0[0]) + a2.y * tanh9(c0[1]) +
                    a2.z * tanh9(c0[2]) + a2.w * tanh9(c0[3]);
            acc1 += a2.x * tanh9(c1[0]) + a2.y * tanh9(c1[1]) +
                    a2.z * tanh9(c1[2]) + a2.w * tanh9(c1[3]);
        }
        acc0 += __shfl_xor(acc0, 16, 64); acc0 += __shfl_xor(acc0, 32, 64);
        acc1 += __shfl_xor(acc1, 16, 64); acc1 += __shfl_xor(acc1, 32, 64);
        if (kg == 0) {
            aggsh[w][n16]      = acc0 * (1.0f / (float)NN);
            aggsh[w][16 + n16] = acc1 * (1.0f / (float)NN);
        }
        __syncthreads();

        // ================= gates (8 waves: R0 R1 I0 I1 N0 N1 G0 G1) =============
        {
            bf16x8 Agh{}, Agl{}, Aih{}, Ail{};
            if (prod != 2) { float x[8]; ld8(&aggsh[n16][k8], x); split8(x, Agh, Agl); }
            if (prod <= 2) {
                float x[8];
                const float* er = emb + (size_t)skill[b * TT + t] * HH;
                ld8(er + k8, x); split8(x, Aih, Ail);
            }
            f32x4 C = {bias1, bias1, bias1, bias1};
            if (prod <= 1) {
                C = MFMA16(Agh, F0h, C); C = MFMA16(Agh, F0l, C); C = MFMA16(Agl, F0h, C);
                C = MFMA16(Aih, F1h, C); C = MFMA16(Aih, F1l, C); C = MFMA16(Ail, F1h, C);
            } else if (prod == 2) {
                C = MFMA16(Aih, F0h, C); C = MFMA16(Aih, F0l, C); C = MFMA16(Ail, F0h, C);
            } else {
                C = MFMA16(Agh, F0h, C); C = MFMA16(Agh, F0l, C); C = MFMA16(Agl, F0h, C);
            }
            float* dst = (prod == 0) ? &grsh[0][0] : (prod == 1) ? &gish[0][0]
                       : (prod == 2) ? &gnsh[0][0] : &ggsh[0][0];
            if (kg < 2) {
#pragma unroll
                for (int j = 0; j < 4; ++j) dst[(4 * kg + j) * 33 + rowb] = C[j];
            }
        }
        __syncthreads();

        // ================= elementwise: hn (LDS-resident hidden) ================
        if (tid < 256) {
            const int row = tid >> 5, h = tid & 31;
            const float rg = sigmoid9(grsh[row][h]);
            const float ig = sigmoid9(gish[row][h]);
            const float ns = tanh9(gnsh[row][h] + rg * ggsh[row][h]);
            const float hn = (1.f - ig) * ns + ig * hnsh[row][h];
            hnsh[row][h] = hn;
            hist[(size_t)t * (BSZ * NN * HH) + (size_t)(node0 + row) * HH + h] = hn;
        }
        __syncthreads();

        // ================= S/V projections (waves 0-3) =================
        if (w < 4) {
            const int p2 = w >> 1;      // 0:S(ssh) 1:V(rvsh)
            bf16x8 Hh, Hl; float x[8];
            ld8(&hnsh[n16][k8], x); split8(x, Hh, Hl);
            f32x4 C = {0.f, 0.f, 0.f, 0.f};
            C = MFMA16(Hh, G0h, C); C = MFMA16(Hh, G0l, C); C = MFMA16(Hl, G0h, C);
            if (kg < 2) {
                if (p2 == 0) {
#pragma unroll
                    for (int j = 0; j < 4; ++j) ssh[4 * kg + j][rowb] = (_Float16)C[j];
                } else {
#pragma unroll
                    for (int j = 0; j < 4; ++j) rvsh[4 * kg + j][rowb] = C[j];
                }
            }
        }

        // ========= exchange: 32 x 16B sc1 stores + relaxed flag + spin ==========
        if (t < NSTEP - 1) {
            __syncthreads();   // ssh complete; also drains each wave's vmcnt
            _Float16* dstb = sbuf + (size_t)(t + 1) * SLAB_F16 + (size_t)b * BSLAB_F16
                           + (size_t)grp * (NODES_PER_BLK * HH);
            if (tid < 32) {
                f16x8 v = *(const f16x8*)&ssh[tid >> 2][(tid & 3) * 8];
                unsigned long long ad = (unsigned long long)dstb + (unsigned long long)tid * 16ull;
                asm volatile("global_store_dwordx4 %0, %1, off sc1" :: "v"(ad), "v"(v) : "memory");
            }
            if (tid == 0) {
                asm volatile("s_waitcnt vmcnt(0)" ::: "memory");  // stores at MALL
                __hip_atomic_fetch_add(&cnt[b * 16], 1u, __ATOMIC_RELAXED, __HIP_MEMORY_SCOPE_AGENT);
                const unsigned tgt = (unsigned)(BLKS_PER_B * (t + 1));
                while (__hip_atomic_load(&cnt[b * 16], __ATOMIC_RELAXED, __HIP_MEMORY_SCOPE_AGENT) < tgt)
                    __builtin_amdgcn_s_sleep(2);
            }
            __syncthreads();
        }
    }
}

// ---------------- final head kernel: P1/P2/O for all node-steps ----------------
#define CHUNK 8
__global__ __launch_bounds__(512, 6) void k_head(
    const float* __restrict__ hist,    // [NSTEP][BSZ*NN][HH] (post-update hidden)
    const float* __restrict__ W_o1, const float* __restrict__ b_o1,
    const float* __restrict__ W_o2, const float* __restrict__ b_o2,
    const float* __restrict__ W_o3, const float* __restrict__ b_o3,
    float* __restrict__ out)
{
    __shared__ alignas(16) float tsh[8][16][36];
    const int tid = threadIdx.x;
    const int w = tid >> 6, lane = tid & 63;
    const int n16 = lane & 15, kg = lane >> 4, k8 = kg * 8;

    bf16x8 W1h[2], W1l[2], W2h[2], W2l[2], W3h[2], W3l[2];
    float bb1[2], bb2[2], bb3[2];
#pragma unroll
    for (int hf = 0; hf < 2; ++hf) {
        const int rowb = hf * 16 + n16;
        loadB_hl(W_o1 + (size_t)rowb * HH + k8, W1h[hf], W1l[hf]); bb1[hf] = b_o1[rowb];
        loadB_hl(W_o2 + (size_t)rowb * HH + k8, W2h[hf], W2l[hf]); bb2[hf] = b_o2[rowb];
        loadB_hl(W_o3 + (size_t)rowb * HH + k8, W3h[hf], W3l[hf]); bb3[hf] = b_o3[rowb];
    }

    const int wgid = blockIdx.x * 8 + w;
#pragma unroll 1
    for (int c = 0; c < CHUNK; ++c) {
        const int cid = wgid * CHUNK + c;
        const int rc = cid % 12;
        const int tt = (cid / 12) % NSTEP;
        const int bb = cid / (12 * NSTEP);

        const float* hrow = hist + ((size_t)tt * BSZ * NN + (size_t)bb * NN + rc * 16) * HH;
        float x[8];
        bf16x8 Ah, Al;
        ld8(hrow + (size_t)n16 * HH + k8, x);
        split8(x, Ah, Al);

#pragma unroll
        for (int hf = 0; hf < 2; ++hf) {
            f32x4 C = {bb1[hf], bb1[hf], bb1[hf], bb1[hf]};
            C = MFMA16(Ah, W1h[hf], C); C = MFMA16(Ah, W1l[hf], C); C = MFMA16(Al, W1h[hf], C);
#pragma unroll
            for (int j = 0; j < 4; ++j) tsh[w][4 * kg + j][hf * 16 + n16] = relu(C[j]);
        }
        ld8(&tsh[w][n16][k8], x);
        split8(x, Ah, Al);

#pragma unroll
        for (int hf = 0; hf < 2; ++hf) {
            f32x4 C = {bb2[hf], bb2[hf], bb2[hf], bb2[hf]};
            C = MFMA16(Ah, W2h[hf], C); C = MFMA16(Ah, W2l[hf], C); C = MFMA16(Al, W2h[hf], C);
#pragma unroll
            for (int j = 0; j < 4; ++j) tsh[w][4 * kg + j][hf * 16 + n16] = relu(C[j]);
        }
        ld8(&tsh[w][n16][k8], x);
        split8(x, Ah, Al);

        float* obase = out + (((size_t)bb * NSTEP + tt) * NN + rc * 16) * HH;
#pragma unroll
        for (int hf = 0; hf < 2; ++hf) {
            f32x4 C = {bb3[hf], bb3[hf], bb3[hf], bb3[hf]};
            C = MFMA16(Ah, W3h[hf], C); C = MFMA16(Ah, W3l[hf], C); C = MFMA16(Al, W3h[hf], C);
#pragma unroll
            for (int j = 0; j < 4; ++j)
                obase[(size_t)(4 * kg + j) * HH + hf * 16 + n16] = C[j];
        }
    }
}

extern "C" void kernel_launch(void* const* d_in, const int* in_sizes, int n_in,
                              void* d_out, int out_size, void* d_ws, size_t ws_size,
                              hipStream_t stream) {
    const int*   skill = (const int*)d_in[0];
    const float* adj   = (const float*)d_in[1];
    const float* emb   = (const float*)d_in[2];
    const float* Wmsg1 = (const float*)d_in[3];
    const float* bmsg1 = (const float*)d_in[4];
    const float* Wmsg2 = (const float*)d_in[5];
    const float* bmsg2 = (const float*)d_in[6];
    const float* W_hr  = (const float*)d_in[7];
    const float* W_hi  = (const float*)d_in[8];
    const float* W_hh  = (const float*)d_in[9];
    const float* W_ir  = (const float*)d_in[10];
    const float* b_ir  = (const float*)d_in[11];
    const float* W_ii  = (const float*)d_in[12];
    const float* b_ii  = (const float*)d_in[13];
    const float* W_in  = (const float*)d_in[14];
    const float* b_in  = (const float*)d_in[15];
    const float* W_o1  = (const float*)d_in[16];
    const float* b_o1  = (const float*)d_in[17];
    const float* W_o2  = (const float*)d_in[18];
    const float* b_o2  = (const float*)d_in[19];
    const float* W_o3  = (const float*)d_in[20];
    const float* b_o3  = (const float*)d_in[21];
    float* out = (float*)d_out;

    const size_t NH = (size_t)BSZ * NN * HH;     // 196608 elements
    char* base = (char*)d_ws;
    unsigned* cnt  = (unsigned*)base;                              // 32×16 u32 = 2 KB
    _Float16* sbuf = (_Float16*)(base + 2048);                     // 49 slabs × 512 KB
    float*    hist = (float*)(base + 2048 + (size_t)NSTEP * SLAB_F16 * 2);

    // zero: counters + slab 0 (read at t=0)
    (void)hipMemsetAsync(d_ws, 0, 2048 + (size_t)SLAB_F16 * 2, stream);

    k_all<<<NBLK, 512, 0, stream>>>(
        skill, adj, emb, Wmsg1, bmsg1, Wmsg2, bmsg2,
        W_hr, W_hi, W_hh, W_ir, b_ir, W_ii, b_ii, W_in, b_in,
        sbuf, cnt, hist);

    // head over all 49*6144 node-steps
    k_head<<<294, 512, 0, stream>>>(hist, W_o1, b_o1, W_o2, b_o2, W_o3, b_o3, out);
}

// Round 14
// 966.801 us; speedup vs baseline: 3.4100x; 1.0336x over previous
//
#include <hip/hip_runtime.h>
#include <hip/hip_bf16.h>

#define BSZ 32
#define TT 50
#define NN 192
#define HH 32
#define NSTEP (TT - 1)
#define NODES_PER_BLK 8
#define BLKS_PER_B (NN / NODES_PER_BLK)   // 24
#define NBLK (BSZ * BLKS_PER_B)           // 768

#define BSLAB_F16 8192                    // f16 per b within a slab (6144 data + pad)
#define SLAB_F16 (BSZ * BSLAB_F16)        // 262144 f16 = 512 KB per step

typedef __attribute__((ext_vector_type(8))) short bf16x8;
typedef __attribute__((ext_vector_type(8))) _Float16 f16x8;
typedef __attribute__((ext_vector_type(2))) _Float16 f16x2;
typedef __attribute__((ext_vector_type(4))) float f32x4;

#define MFMA16(A, B, C) __builtin_amdgcn_mfma_f32_16x16x32_bf16((A), (B), (C), 0, 0, 0)
#define MFMAH(A, B, C)  __builtin_amdgcn_mfma_f32_16x16x32_f16((A), (B), (C), 0, 0, 0)

// 2*log2(e): tanh(x) = 1 - 2/(1 + 2^(C2*x))
#define C2 2.885390081777927f

#if defined(__has_builtin)
#if __has_builtin(__builtin_amdgcn_exp2f)
#define EXP2(x) __builtin_amdgcn_exp2f(x)
#endif
#endif
#ifndef EXP2
#define EXP2(x) __expf(0.69314718056f * (x))
#endif

__device__ __forceinline__ float fast_rcp(float x) { return __builtin_amdgcn_rcpf(x); }
__device__ __forceinline__ float relu(float x) { return x > 0.0f ? x : 0.0f; }

// degree-9 odd polynomial tanh on [-1.2, 1.2], abs err <~4e-5 in-range (f32).
__device__ __forceinline__ float tanh9(float x) {
    x = fminf(1.2f, fmaxf(-1.2f, x));
    float u = x * x;
    float h = __builtin_fmaf(u, 0.0090878f, -0.0447732f);
    h = __builtin_fmaf(u, h, 0.1302534f);
    h = __builtin_fmaf(u, h, -0.3329694f);
    h = __builtin_fmaf(u, h, 1.0000104f);
    return x * h;
}
__device__ __forceinline__ float sigmoid9(float x) {
    return __builtin_fmaf(0.5f, tanh9(0.5f * x), 0.5f);
}

__device__ __forceinline__ f16x2 splat2(float v) {
    f16x2 r; r[0] = (_Float16)v; r[1] = (_Float16)v; return r;
}
__device__ __forceinline__ f16x2 tanh9h2(f16x2 x) {
    x = __builtin_elementwise_min(__builtin_elementwise_max(x, splat2(-1.2f)), splat2(1.2f));
    f16x2 u = x * x;
    f16x2 h = __builtin_elementwise_fma(u, splat2(0.0090878f), splat2(-0.0447732f));
    h = __builtin_elementwise_fma(u, h, splat2(0.1302534f));
    h = __builtin_elementwise_fma(u, h, splat2(-0.3329694f));
    h = __builtin_elementwise_fma(u, h, splat2(1.0000104f));
    return x * h;
}

union U8 { bf16x8 v; __hip_bfloat162 p[4]; };
union UH { f16x8 v; f16x2 p[4]; };

__device__ __forceinline__ void ld8(const float* p, float* x) {
    const float4* q = (const float4*)p;
    float4 a = q[0], c = q[1];
    x[0] = a.x; x[1] = a.y; x[2] = a.z; x[3] = a.w;
    x[4] = c.x; x[5] = c.y; x[6] = c.z; x[7] = c.w;
}
__device__ __forceinline__ f16x8 packh8(const float* x) {
    UH u;
#pragma unroll
    for (int i = 0; i < 8; ++i) u.v[i] = (_Float16)x[i];
    return u.v;
}
__device__ __forceinline__ void split8(const float* x, bf16x8& hi, bf16x8& lo) {
    U8 H, L;
#pragma unroll
    for (int i = 0; i < 4; ++i) {
        __hip_bfloat162 h = __float22bfloat162_rn(make_float2(x[2 * i], x[2 * i + 1]));
        float2 hf = __bfloat1622float2(h);
        H.p[i] = h;
        L.p[i] = __float22bfloat162_rn(make_float2(x[2 * i] - hf.x, x[2 * i + 1] - hf.y));
    }
    hi = H.v; lo = L.v;
}
__device__ __forceinline__ void loadB_hl(const float* Wrow, bf16x8& h, bf16x8& l) {
    float x[8];
    ld8(Wrow, x);
    split8(x, h, l);
}

// Persistent kernel v6 = v5 exchange (per-step slabs, sc1 write-through, relaxed
// flags) + r12 pipe-split phase A (msg1 poly on VALU pipe, msg2 exp2/rcp on the
// trans pipe with C2 folded into B-frags and adj folded via A0).
__global__ __launch_bounds__(512, 6) void k_all(
    const int* __restrict__ skill, const float* __restrict__ adj,
    const float* __restrict__ emb,
    const float* __restrict__ Wmsg1, const float* __restrict__ bmsg1,
    const float* __restrict__ Wmsg2, const float* __restrict__ bmsg2,
    const float* __restrict__ W_hr, const float* __restrict__ W_hi, const float* __restrict__ W_hh,
    const float* __restrict__ W_ir, const float* __restrict__ b_ir,
    const float* __restrict__ W_ii, const float* __restrict__ b_ii,
    const float* __restrict__ W_in, const float* __restrict__ b_in,
    _Float16* __restrict__ sbuf, unsigned* __restrict__ cnt, float* __restrict__ hist)
{
    __shared__ alignas(16) _Float16 spsh[NN][40];   // send_p[b] staged f16
    __shared__ alignas(16) float adjsh[8][NN];      // adj rows (loaded once)
    __shared__ alignas(16) float aggsh[16][36];     // rows 0-7 live, 8-15 zero
    __shared__ alignas(16) float hnsh[16][36];      // persistent hidden
    __shared__ alignas(16) float rvsh[8][36];       // block-local recv proj
    __shared__ alignas(16) _Float16 ssh[8][32];     // send bounce (512 B)
    __shared__ float grsh[8][33], gish[8][33], gnsh[8][33], ggsh[8][33];

    const int tid = threadIdx.x;
    const int w = tid >> 6, lane = tid & 63;
    const int n16 = lane & 15, kg = lane >> 4, k8 = kg * 8;
    // Same-b blocks share blockIdx%8 (XCD grouping; PERF only — correctness is
    // mapping-independent via first-touch slabs + sc1 write-through).
    const int m = blockIdx.x;
    const int b = (m & 7) * 4 + (m >> 3) / BLKS_PER_B;
    const int grp = (m >> 3) % BLKS_PER_B;
    const int node0 = b * NN + grp * NODES_PER_BLK;  // global node base
    const int node = node0 + w;
    const int prod = w >> 1, hf = w & 1;
    const int rowb = hf * 16 + n16;

    // ---- one-time init ----
    for (int i = tid; i < 16 * 36; i += 512) { ((float*)aggsh)[i] = 0.f; ((float*)hnsh)[i] = 0.f; }
    for (int i = tid; i < 8 * 36; i += 512) ((float*)rvsh)[i] = 0.f;
    float A0w;
    {
        const float* ar = adj + (size_t)node * NN;
        float a0 = ar[lane], a1 = ar[lane + 64], a2v = ar[lane + 128];
        adjsh[w][lane] = a0; adjsh[w][lane + 64] = a1; adjsh[w][lane + 128] = a2v;
        float s = a0 + a1 + a2v;
#pragma unroll
        for (int mm = 1; mm < 64; mm <<= 1) s += __shfl_xor(s, mm, 64);
        A0w = s;
    }
    float b1r[8];
    ld8(bmsg1 + k8, b1r);
    // phase-A B-frags: C2 * W2^T in f16 (MFMA then outputs the exp2 argument)
    f16x8 Bh0, Bh1;
    {
        float x[8];
        ld8(Wmsg2 + (size_t)n16 * HH + k8, x);
#pragma unroll
        for (int i = 0; i < 8; ++i) x[i] *= C2;
        Bh0 = packh8(x);
        ld8(Wmsg2 + (size_t)(16 + n16) * HH + k8, x);
#pragma unroll
        for (int i = 0; i < 8; ++i) x[i] *= C2;
        Bh1 = packh8(x);
    }
    const float cb2_0 = C2 * bmsg2[n16], cb2_1 = C2 * bmsg2[16 + n16];

    bf16x8 F0h{}, F0l{}, F1h{}, F1l{}, G0h{}, G0l{};
    float bias1 = 0.f;
    if (prod == 0) {            // R gate; later S (send)
        loadB_hl(W_hr + (size_t)rowb * HH + k8, F0h, F0l);
        loadB_hl(W_ir + (size_t)rowb * HH + k8, F1h, F1l);
        bias1 = b_ir[rowb];
        loadB_hl(Wmsg1 + (size_t)rowb * 2 * HH + k8, G0h, G0l);      // W_send
    } else if (prod == 1) {     // I gate; later V (recv)
        loadB_hl(W_hi + (size_t)rowb * HH + k8, F0h, F0l);
        loadB_hl(W_ii + (size_t)rowb * HH + k8, F1h, F1l);
        bias1 = b_ii[rowb];
        loadB_hl(Wmsg1 + (size_t)rowb * 2 * HH + HH + k8, G0h, G0l); // W_recv
    } else if (prod == 2) {     // N gate
        loadB_hl(W_in + (size_t)rowb * HH + k8, F0h, F0l);
        bias1 = b_in[rowb];
    } else {                    // G = agg @ W_hh^T
        loadB_hl(W_hh + (size_t)rowb * HH + k8, F0h, F0l);
    }
    __syncthreads();

    for (int t = 0; t < NSTEP; ++t) {
        // ---- stage send_p[b] from slab t via PLAIN cached loads (first touch) ----
        {
            const f16x8* src = (const f16x8*)(sbuf + (size_t)t * SLAB_F16 + (size_t)b * BSLAB_F16);
            f16x8 v0 = src[tid];
            *(f16x8*)&spsh[tid >> 2][(tid & 3) * 8] = v0;
            if (tid < 256) {
                const int c = tid + 512;
                f16x8 v1 = src[c];
                *(f16x8*)&spsh[c >> 2][(c & 3) * 8] = v1;
            }
        }
        // rvp = f16(recv_local + b1)
        UH rv;
        {
            float x[8];
            ld8(&rvsh[w][k8], x);
#pragma unroll
            for (int i = 0; i < 8; ++i) rv.v[i] = (_Float16)(x[i] + b1r[i]);
        }
        __syncthreads();

        // ================= Phase A (poly on VALU pipe, exp2/rcp on trans pipe) ==
        float acc0 = 0.f, acc1 = 0.f;   // accumulate sum(adj * inv)
#pragma unroll 2
        for (int s0 = 0; s0 < NN; s0 += 16) {
            UH a, tv;
            a.v = *(const f16x8*)&spsh[s0 + n16][k8];
#pragma unroll
            for (int i = 0; i < 4; ++i)
                tv.p[i] = tanh9h2(a.p[i] + rv.p[i]);
            f32x4 c0 = MFMAH(tv.v, Bh0, ((f32x4){cb2_0, cb2_0, cb2_0, cb2_0}));
            f32x4 c1 = MFMAH(tv.v, Bh1, ((f32x4){cb2_1, cb2_1, cb2_1, cb2_1}));
            const float4 a2 = *(const float4*)&adjsh[w][s0 + 4 * kg];
            // tanh = 1 - 2*inv, inv = 1/(1+2^(C2*y)); sum(adj*tanh) = A0 - 2*sum(adj*inv)
            acc0 = __builtin_fmaf(a2.x, fast_rcp(1.f + EXP2(c0[0])), acc0);
            acc0 = __builtin_fmaf(a2.y, fast_rcp(1.f + EXP2(c0[1])), acc0);
            acc0 = __builtin_fmaf(a2.z, fast_rcp(1.f + EXP2(c0[2])), acc0);
            acc0 = __builtin_fmaf(a2.w, fast_rcp(1.f + EXP2(c0[3])), acc0);
            acc1 = __builtin_fmaf(a2.x, fast_rcp(1.f + EXP2(c1[0])), acc1);
            acc1 = __builtin_fmaf(a2.y, fast_rcp(1.f + EXP2(c1[1])), acc1);
            acc1 = __builtin_fmaf(a2.z, fast_rcp(1.f + EXP2(c1[2])), acc1);
            acc1 = __builtin_fmaf(a2.w, fast_rcp(1.f + EXP2(c1[3])), acc1);
        }
        acc0 += __shfl_xor(acc0, 16, 64); acc0 += __shfl_xor(acc0, 32, 64);
        acc1 += __shfl_xor(acc1, 16, 64); acc1 += __shfl_xor(acc1, 32, 64);
        if (kg == 0) {
            aggsh[w][n16]      = (A0w - 2.f * acc0) * (1.0f / (float)NN);
            aggsh[w][16 + n16] = (A0w - 2.f * acc1) * (1.0f / (float)NN);
        }
        __syncthreads();

        // ================= gates (8 waves: R0 R1 I0 I1 N0 N1 G0 G1) =============
        {
            bf16x8 Agh{}, Agl{}, Aih{}, Ail{};
            if (prod != 2) { float x[8]; ld8(&aggsh[n16][k8], x); split8(x, Agh, Agl); }
            if (prod <= 2) {
                float x[8];
                const float* er = emb + (size_t)skill[b * TT + t] * HH;
                ld8(er + k8, x); split8(x, Aih, Ail);
            }
            f32x4 C = {bias1, bias1, bias1, bias1};
            if (prod <= 1) {
                C = MFMA16(Agh, F0h, C); C = MFMA16(Agh, F0l, C); C = MFMA16(Agl, F0h, C);
                C = MFMA16(Aih, F1h, C); C = MFMA16(Aih, F1l, C); C = MFMA16(Ail, F1h, C);
            } else if (prod == 2) {
                C = MFMA16(Aih, F0h, C); C = MFMA16(Aih, F0l, C); C = MFMA16(Ail, F0h, C);
            } else {
                C = MFMA16(Agh, F0h, C); C = MFMA16(Agh, F0l, C); C = MFMA16(Agl, F0h, C);
            }
            float* dst = (prod == 0) ? &grsh[0][0] : (prod == 1) ? &gish[0][0]
                       : (prod == 2) ? &gnsh[0][0] : &ggsh[0][0];
            if (kg < 2) {
#pragma unroll
                for (int j = 0; j < 4; ++j) dst[(4 * kg + j) * 33 + rowb] = C[j];
            }
        }
        __syncthreads();

        // ================= elementwise: hn (LDS-resident hidden) ================
        if (tid < 256) {
            const int row = tid >> 5, h = tid & 31;
            const float rg = sigmoid9(grsh[row][h]);
            const float ig = sigmoid9(gish[row][h]);
            const float ns = tanh9(gnsh[row][h] + rg * ggsh[row][h]);
            const float hn = (1.f - ig) * ns + ig * hnsh[row][h];
            hnsh[row][h] = hn;
            hist[(size_t)t * (BSZ * NN * HH) + (size_t)(node0 + row) * HH + h] = hn;
        }
        __syncthreads();

        // ================= S/V projections (waves 0-3) =================
        if (w < 4) {
            const int p2 = w >> 1;      // 0:S(ssh) 1:V(rvsh)
            bf16x8 Hh, Hl; float x[8];
            ld8(&hnsh[n16][k8], x); split8(x, Hh, Hl);
            f32x4 C = {0.f, 0.f, 0.f, 0.f};
            C = MFMA16(Hh, G0h, C); C = MFMA16(Hh, G0l, C); C = MFMA16(Hl, G0h, C);
            if (kg < 2) {
                if (p2 == 0) {
#pragma unroll
                    for (int j = 0; j < 4; ++j) ssh[4 * kg + j][rowb] = (_Float16)C[j];
                } else {
#pragma unroll
                    for (int j = 0; j < 4; ++j) rvsh[4 * kg + j][rowb] = C[j];
                }
            }
        }

        // ========= exchange: 32 x 16B sc1 stores + relaxed flag + spin ==========
        if (t < NSTEP - 1) {
            __syncthreads();   // ssh complete; also drains each wave's vmcnt
            _Float16* dstb = sbuf + (size_t)(t + 1) * SLAB_F16 + (size_t)b * BSLAB_F16
                           + (size_t)grp * (NODES_PER_BLK * HH);
            if (tid < 32) {
                f16x8 v = *(const f16x8*)&ssh[tid >> 2][(tid & 3) * 8];
                unsigned long long ad = (unsigned long long)dstb + (unsigned long long)tid * 16ull;
                asm volatile("global_store_dwordx4 %0, %1, off sc1" :: "v"(ad), "v"(v) : "memory");
            }
            if (tid == 0) {
                asm volatile("s_waitcnt vmcnt(0)" ::: "memory");  // stores at MALL
                __hip_atomic_fetch_add(&cnt[b * 16], 1u, __ATOMIC_RELAXED, __HIP_MEMORY_SCOPE_AGENT);
                const unsigned tgt = (unsigned)(BLKS_PER_B * (t + 1));
                while (__hip_atomic_load(&cnt[b * 16], __ATOMIC_RELAXED, __HIP_MEMORY_SCOPE_AGENT) < tgt)
                    __builtin_amdgcn_s_sleep(2);
            }
            __syncthreads();
        }
    }
}

// ---------------- final head kernel: P1/P2/O for all node-steps ----------------
#define CHUNK 8
__global__ __launch_bounds__(512, 6) void k_head(
    const float* __restrict__ hist,    // [NSTEP][BSZ*NN][HH] (post-update hidden)
    const float* __restrict__ W_o1, const float* __restrict__ b_o1,
    const float* __restrict__ W_o2, const float* __restrict__ b_o2,
    const float* __restrict__ W_o3, const float* __restrict__ b_o3,
    float* __restrict__ out)
{
    __shared__ alignas(16) float tsh[8][16][36];
    const int tid = threadIdx.x;
    const int w = tid >> 6, lane = tid & 63;
    const int n16 = lane & 15, kg = lane >> 4, k8 = kg * 8;

    bf16x8 W1h[2], W1l[2], W2h[2], W2l[2], W3h[2], W3l[2];
    float bb1[2], bb2[2], bb3[2];
#pragma unroll
    for (int hf = 0; hf < 2; ++hf) {
        const int rowb = hf * 16 + n16;
        loadB_hl(W_o1 + (size_t)rowb * HH + k8, W1h[hf], W1l[hf]); bb1[hf] = b_o1[rowb];
        loadB_hl(W_o2 + (size_t)rowb * HH + k8, W2h[hf], W2l[hf]); bb2[hf] = b_o2[rowb];
        loadB_hl(W_o3 + (size_t)rowb * HH + k8, W3h[hf], W3l[hf]); bb3[hf] = b_o3[rowb];
    }

    const int wgid = blockIdx.x * 8 + w;
#pragma unroll 1
    for (int c = 0; c < CHUNK; ++c) {
        const int cid = wgid * CHUNK + c;
        const int rc = cid % 12;
        const int tt = (cid / 12) % NSTEP;
        const int bb = cid / (12 * NSTEP);

        const float* hrow = hist + ((size_t)tt * BSZ * NN + (size_t)bb * NN + rc * 16) * HH;
        float x[8];
        bf16x8 Ah, Al;
        ld8(hrow + (size_t)n16 * HH + k8, x);
        split8(x, Ah, Al);

#pragma unroll
        for (int hf = 0; hf < 2; ++hf) {
            f32x4 C = {bb1[hf], bb1[hf], bb1[hf], bb1[hf]};
            C = MFMA16(Ah, W1h[hf], C); C = MFMA16(Ah, W1l[hf], C); C = MFMA16(Al, W1h[hf], C);
#pragma unroll
            for (int j = 0; j < 4; ++j) tsh[w][4 * kg + j][hf * 16 + n16] = relu(C[j]);
        }
        ld8(&tsh[w][n16][k8], x);
        split8(x, Ah, Al);

#pragma unroll
        for (int hf = 0; hf < 2; ++hf) {
            f32x4 C = {bb2[hf], bb2[hf], bb2[hf], bb2[hf]};
            C = MFMA16(Ah, W2h[hf], C); C = MFMA16(Ah, W2l[hf], C); C = MFMA16(Al, W2h[hf], C);
#pragma unroll
            for (int j = 0; j < 4; ++j) tsh[w][4 * kg + j][hf * 16 + n16] = relu(C[j]);
        }
        ld8(&tsh[w][n16][k8], x);
        split8(x, Ah, Al);

        float* obase = out + (((size_t)bb * NSTEP + tt) * NN + rc * 16) * HH;
#pragma unroll
        for (int hf = 0; hf < 2; ++hf) {
            f32x4 C = {bb3[hf], bb3[hf], bb3[hf], bb3[hf]};
            C = MFMA16(Ah, W3h[hf], C); C = MFMA16(Ah, W3l[hf], C); C = MFMA16(Al, W3h[hf], C);
#pragma unroll
            for (int j = 0; j < 4; ++j)
                obase[(size_t)(4 * kg + j) * HH + hf * 16 + n16] = C[j];
        }
    }
}

extern "C" void kernel_launch(void* const* d_in, const int* in_sizes, int n_in,
                              void* d_out, int out_size, void* d_ws, size_t ws_size,
                              hipStream_t stream) {
    const int*   skill = (const int*)d_in[0];
    const float* adj   = (const float*)d_in[1];
    const float* emb   = (const float*)d_in[2];
    const float* Wmsg1 = (const float*)d_in[3];
    const float* bmsg1 = (const float*)d_in[4];
    const float* Wmsg2 = (const float*)d_in[5];
    const float* bmsg2 = (const float*)d_in[6];
    const float* W_hr  = (const float*)d_in[7];
    const float* W_hi  = (const float*)d_in[8];
    const float* W_hh  = (const float*)d_in[9];
    const float* W_ir  = (const float*)d_in[10];
    const float* b_ir  = (const float*)d_in[11];
    const float* W_ii  = (const float*)d_in[12];
    const float* b_ii  = (const float*)d_in[13];
    const float* W_in  = (const float*)d_in[14];
    const float* b_in  = (const float*)d_in[15];
    const float* W_o1  = (const float*)d_in[16];
    const float* b_o1  = (const float*)d_in[17];
    const float* W_o2  = (const float*)d_in[18];
    const float* b_o2  = (const float*)d_in[19];
    const float* W_o3  = (const float*)d_in[20];
    const float* b_o3  = (const float*)d_in[21];
    float* out = (float*)d_out;

    char* base = (char*)d_ws;
    unsigned* cnt  = (unsigned*)base;                              // 32×16 u32 = 2 KB
    _Float16* sbuf = (_Float16*)(base + 2048);                     // 49 slabs × 512 KB
    float*    hist = (float*)(base + 2048 + (size_t)NSTEP * SLAB_F16 * 2);

    // zero: counters + slab 0 (read at t=0)
    (void)hipMemsetAsync(d_ws, 0, 2048 + (size_t)SLAB_F16 * 2, stream);

    k_all<<<NBLK, 512, 0, stream>>>(
        skill, adj, emb, Wmsg1, bmsg1, Wmsg2, bmsg2,
        W_hr, W_hi, W_hh, W_ir, b_ir, W_ii, b_ii, W_in, b_in,
        sbuf, cnt, hist);

    // head over all 49*6144 node-steps
    k_head<<<294, 512, 0, stream>>>(hist, W_o1, b_o1, W_o2, b_o2, W_o3, b_o3, out);
}